// Round 3
// baseline (5697.561 us; speedup 1.0000x reference)
//
#include <hip/hip_runtime.h>

// LSTM_Block B=512,T=168,I=64,H=256x2 — persistent cooperative kernel.
// 256 blocks x 256 thr (4 waves, 1 block/CU, 0 LDS). Diagonal pipeline:
// super-step s runs L1(t=s) on blocks 128..255, L2(t=s-1) on blocks 0..127.
// Grid barrier: monotonic counter, release add + relaxed spin + acquire fence.
// GEMMs: bf16x3-split MFMA (hi*hi + lo*hi + hi*lo), fp32 c-state.

#define B_ 512
#define T_ 168
#define I_ 64
#define H_ 256
#define NBLK 256

typedef __attribute__((ext_vector_type(8))) short short8;
typedef __attribute__((ext_vector_type(4))) float f32x4;
typedef unsigned short u16;

__device__ __forceinline__ u16 f2bf(float f) {           // RNE
    unsigned u = __float_as_uint(f);
    return (u16)((u + 0x7fff + ((u >> 16) & 1)) >> 16);
}
__device__ __forceinline__ float bf2f(u16 b) { return __uint_as_float(((unsigned)b) << 16); }
__device__ __forceinline__ float sigm(float x) { return 1.f / (1.f + __expf(-x)); }
__device__ __forceinline__ float tanh_c(float x) {
    float xc = fminf(fmaxf(x, -15.f), 15.f);
    float e = __expf(2.f * xc);
    return (e - 1.f) / (e + 1.f);
}

// W packed [col][K], col = gate*256+jh (PyTorch row order i,f,g,o), bf16 hi/lo.
__global__ void prep_w(const float* __restrict__ W_ih, const float* __restrict__ W_hh,
                       const float* __restrict__ b_ih, const float* __restrict__ b_hh,
                       u16* __restrict__ Whi, u16* __restrict__ Wlo, float* __restrict__ BP,
                       int K, int I) {
    int j = blockIdx.y;
    int k = blockIdx.x * 256 + threadIdx.x;
    if (k < K) {
        float v = (k < I) ? W_ih[(size_t)j * I + k] : W_hh[(size_t)j * H_ + (k - I)];
        u16 hi = f2bf(v);
        Whi[(size_t)j * K + k] = hi;
        Wlo[(size_t)j * K + k] = f2bf(v - bf2f(hi));
    }
    if (blockIdx.x == 0 && threadIdx.x == 0) BP[j] = b_ih[j] + b_hh[j];
}

// x [b][t][i] fp32 -> X [t][b][i] bf16 hi/lo (contiguous per-step slice)
__global__ void prep_x_t(const float* __restrict__ x, u16* __restrict__ Xhi, u16* __restrict__ Xlo) {
    int n = B_ * T_ * I_;
    for (int idx = blockIdx.x * blockDim.x + threadIdx.x; idx < n; idx += gridDim.x * blockDim.x) {
        float v = x[idx];
        int i = idx & 63, bt = idx >> 6;
        int t = bt % T_, b = bt / T_;
        size_t o = ((size_t)t * B_ + b) * I_ + i;
        u16 hi = f2bf(v);
        Xhi[o] = hi;
        Xlo[o] = f2bf(v - bf2f(hi));
    }
}

struct PArgs {
    const u16 *Xhi, *Xlo;
    u16 *H1hi[2], *H1lo[2], *H2hi[2], *H2lo[2];
    float *C1, *C2;
    const u16 *W1hi, *W1lo, *W2hi, *W2lo;
    const float *BP1, *BP2;
    float *out;
    unsigned *bar;
};

__global__ __launch_bounds__(256, 1) void lstm_persist(PArgs a) {
    const int blk = blockIdx.x;
    const bool isL1 = blk >= 128;
    const int sub = isL1 ? (blk - 128) : blk;
    const int bg  = sub & 7;              // b64 group
    const int jh0 = (sub >> 3) << 4;      // 16 jh per block
    const int lane = threadIdx.x & 63;
    const int wave = threadIdx.x >> 6;    // m-tile within b64
    const int lm   = lane & 15;
    const int lk8  = (lane >> 4) << 3;
    const int b0   = bg * 64 + wave * 16;
    const int jh   = jh0 + lm;
    const int K    = isL1 ? (I_ + H_) : (2 * H_);

    const u16* Whi = isL1 ? a.W1hi : a.W2hi;
    const u16* Wlo = isL1 ? a.W1lo : a.W2lo;
    const float* BP = isL1 ? a.BP1 : a.BP2;
    float* C = isL1 ? a.C1 : a.C2;

    const size_t w0 = (size_t)(0 * H_ + jh) * K + lk8;
    const size_t w1 = (size_t)(1 * H_ + jh) * K + lk8;
    const size_t w2 = (size_t)(2 * H_ + jh) * K + lk8;
    const size_t w3 = (size_t)(3 * H_ + jh) * K + lk8;
    const float bi_ = BP[jh], bf_ = BP[H_ + jh], bg_ = BP[2 * H_ + jh], bo_ = BP[3 * H_ + jh];
    const size_t arow = (size_t)(b0 + lm);

    for (int s = 0; s <= T_; ++s) {
        const int t = isL1 ? s : (s - 1);
        const bool active = isL1 ? (t < T_) : (t >= 0);
        if (active) {
            f32x4 acc0 = {0.f,0.f,0.f,0.f}, acc1 = acc0, acc2 = acc0, acc3 = acc0;
            auto DOK = [&](short8 ah, short8 al, int k) {
                short8 wh, wl;
                wh = *(const short8*)(Whi + w0 + k); wl = *(const short8*)(Wlo + w0 + k);
                acc0 = __builtin_amdgcn_mfma_f32_16x16x32_bf16(ah, wh, acc0, 0, 0, 0);
                acc0 = __builtin_amdgcn_mfma_f32_16x16x32_bf16(al, wh, acc0, 0, 0, 0);
                acc0 = __builtin_amdgcn_mfma_f32_16x16x32_bf16(ah, wl, acc0, 0, 0, 0);
                wh = *(const short8*)(Whi + w1 + k); wl = *(const short8*)(Wlo + w1 + k);
                acc1 = __builtin_amdgcn_mfma_f32_16x16x32_bf16(ah, wh, acc1, 0, 0, 0);
                acc1 = __builtin_amdgcn_mfma_f32_16x16x32_bf16(al, wh, acc1, 0, 0, 0);
                acc1 = __builtin_amdgcn_mfma_f32_16x16x32_bf16(ah, wl, acc1, 0, 0, 0);
                wh = *(const short8*)(Whi + w2 + k); wl = *(const short8*)(Wlo + w2 + k);
                acc2 = __builtin_amdgcn_mfma_f32_16x16x32_bf16(ah, wh, acc2, 0, 0, 0);
                acc2 = __builtin_amdgcn_mfma_f32_16x16x32_bf16(al, wh, acc2, 0, 0, 0);
                acc2 = __builtin_amdgcn_mfma_f32_16x16x32_bf16(ah, wl, acc2, 0, 0, 0);
                wh = *(const short8*)(Whi + w3 + k); wl = *(const short8*)(Wlo + w3 + k);
                acc3 = __builtin_amdgcn_mfma_f32_16x16x32_bf16(ah, wh, acc3, 0, 0, 0);
                acc3 = __builtin_amdgcn_mfma_f32_16x16x32_bf16(al, wh, acc3, 0, 0, 0);
                acc3 = __builtin_amdgcn_mfma_f32_16x16x32_bf16(ah, wl, acc3, 0, 0, 0);
            };
            if (isL1) {
                const u16* xh = a.Xhi + ((size_t)t * B_ + b0 + lm) * I_ + lk8;
                const u16* xl = a.Xlo + ((size_t)t * B_ + b0 + lm) * I_ + lk8;
#pragma unroll
                for (int ks = 0; ks < 2; ++ks)
                    DOK(*(const short8*)(xh + ks * 32), *(const short8*)(xl + ks * 32), ks * 32);
                const int rp = (t & 1) ^ 1;          // h1(t-1)
                const u16* hh = a.H1hi[rp] + arow * H_ + lk8;
                const u16* hl = a.H1lo[rp] + arow * H_ + lk8;
#pragma unroll 4
                for (int ks = 0; ks < 8; ++ks)
                    DOK(*(const short8*)(hh + ks * 32), *(const short8*)(hl + ks * 32), I_ + ks * 32);
            } else {
                const int p1 = t & 1;                // h1(t), written by L1 last super-step
                const u16* hh = a.H1hi[p1] + arow * H_ + lk8;
                const u16* hl = a.H1lo[p1] + arow * H_ + lk8;
#pragma unroll 4
                for (int ks = 0; ks < 8; ++ks)
                    DOK(*(const short8*)(hh + ks * 32), *(const short8*)(hl + ks * 32), ks * 32);
                const int rp2 = p1 ^ 1;              // h2(t-1)
                const u16* gh = a.H2hi[rp2] + arow * H_ + lk8;
                const u16* gl = a.H2lo[rp2] + arow * H_ + lk8;
#pragma unroll 4
                for (int ks = 0; ks < 8; ++ks)
                    DOK(*(const short8*)(gh + ks * 32), *(const short8*)(gl + ks * 32), H_ + ks * 32);
            }
            const int wp = t & 1;
            u16* ohi = isL1 ? a.H1hi[wp] : a.H2hi[wp];
            u16* olo = isL1 ? a.H1lo[wp] : a.H2lo[wp];
#pragma unroll
            for (int i = 0; i < 4; ++i) {
                const int b = b0 + ((lane >> 4) << 2) + i;
                float gi = acc0[i] + bi_;
                float gf = acc1[i] + bf_;
                float gg = acc2[i] + bg_;
                float go = acc3[i] + bo_;
                float si = sigm(gi), sf = sigm(gf), tg = tanh_c(gg), so = sigm(go);
                const size_t ci = (size_t)b * H_ + jh;
                float cn = sf * C[ci] + si * tg;
                C[ci] = cn;
                float h = so * tanh_c(cn);
                u16 h16 = f2bf(h);
                ohi[ci] = h16;
                olo[ci] = f2bf(h - bf2f(h16));
                if (!isL1) a.out[((size_t)b * T_ + t) * H_ + jh] = h;
            }
        }
        if (s < T_) {   // no barrier needed after final super-step
            __syncthreads();
            if (threadIdx.x == 0) {
                __hip_atomic_fetch_add(a.bar, 1u, __ATOMIC_RELEASE, __HIP_MEMORY_SCOPE_AGENT);
                const unsigned target = (unsigned)(s + 1) * NBLK;
                while (__hip_atomic_load(a.bar, __ATOMIC_RELAXED, __HIP_MEMORY_SCOPE_AGENT) < target)
                    __builtin_amdgcn_s_sleep(4);
                __builtin_amdgcn_fence(__ATOMIC_ACQUIRE, "agent");
            }
            __syncthreads();
        }
    }
}

extern "C" void kernel_launch(void* const* d_in, const int* in_sizes, int n_in,
                              void* d_out, int out_size, void* d_ws, size_t ws_size,
                              hipStream_t stream) {
    const float* x     = (const float*)d_in[0];
    const float* W_ih1 = (const float*)d_in[1];
    const float* W_hh1 = (const float*)d_in[2];
    const float* b_ih1 = (const float*)d_in[3];
    const float* b_hh1 = (const float*)d_in[4];
    const float* W_ih2 = (const float*)d_in[5];
    const float* W_hh2 = (const float*)d_in[6];
    const float* b_ih2 = (const float*)d_in[7];
    const float* b_hh2 = (const float*)d_in[8];
    (void)in_sizes; (void)n_in; (void)out_size; (void)ws_size;

    size_t off = 0;
    char* base = (char*)d_ws;
    auto alloc = [&](size_t bytes) { void* p = base + off; off = (off + bytes + 255) & ~(size_t)255; return p; };

    const int K1 = I_ + H_;   // 320
    const int K2 = 2 * H_;    // 512
    u16* W1hi = (u16*)alloc((size_t)1024 * K1 * 2);
    u16* W1lo = (u16*)alloc((size_t)1024 * K1 * 2);
    u16* W2hi = (u16*)alloc((size_t)1024 * K2 * 2);
    u16* W2lo = (u16*)alloc((size_t)1024 * K2 * 2);
    float* BP1 = (float*)alloc(1024 * 4);
    float* BP2 = (float*)alloc(1024 * 4);
    u16* Xhi = (u16*)alloc((size_t)B_ * T_ * I_ * 2);
    u16* Xlo = (u16*)alloc((size_t)B_ * T_ * I_ * 2);

    // zero-init block: barrier counter + H dbufs (bf16) + C (fp32)
    char* state0 = base + off;
    unsigned* bar = (unsigned*)alloc(256);
    const size_t HB = (size_t)B_ * H_ * 2;
    PArgs pa;
    pa.H1hi[0] = (u16*)alloc(HB); pa.H1hi[1] = (u16*)alloc(HB);
    pa.H1lo[0] = (u16*)alloc(HB); pa.H1lo[1] = (u16*)alloc(HB);
    pa.H2hi[0] = (u16*)alloc(HB); pa.H2hi[1] = (u16*)alloc(HB);
    pa.H2lo[0] = (u16*)alloc(HB); pa.H2lo[1] = (u16*)alloc(HB);
    pa.C1 = (float*)alloc((size_t)B_ * H_ * 4);
    pa.C2 = (float*)alloc((size_t)B_ * H_ * 4);
    size_t stateBytes = (size_t)((base + off) - state0);

    hipMemsetAsync(state0, 0, stateBytes, stream);
    prep_w<<<dim3(2, 1024), 256, 0, stream>>>(W_ih1, W_hh1, b_ih1, b_hh1, W1hi, W1lo, BP1, K1, I_);
    prep_w<<<dim3(2, 1024), 256, 0, stream>>>(W_ih2, W_hh2, b_ih2, b_hh2, W2hi, W2lo, BP2, K2, H_);
    prep_x_t<<<512, 256, 0, stream>>>(x, Xhi, Xlo);

    pa.Xhi = Xhi; pa.Xlo = Xlo;
    pa.W1hi = W1hi; pa.W1lo = W1lo; pa.W2hi = W2hi; pa.W2lo = W2lo;
    pa.BP1 = BP1; pa.BP2 = BP2;
    pa.out = (float*)d_out;
    pa.bar = bar;

    void* kp[] = {(void*)&pa};
    hipLaunchCooperativeKernel((const void*)lstm_persist, dim3(NBLK), dim3(256), kp, 0, stream);
}

// Round 6
// 3395.074 us; speedup vs baseline: 1.6782x; 1.6782x over previous
//
#include <hip/hip_runtime.h>

// LSTM_Block B=512,T=168,I=64,H=256x2 — persistent kernel v4 (plain launch).
// W entirely in VGPRs (split-K across 4 waves, K zero-padded to 512 both
// layers), C in registers, 48KB LDS for the split-K reduce.
// H exchanged as packed (bf16hi|bf16lo) dwords via u64 RELAXED agent atomics
// (sc-bit coherent loads/stores, no cache-wide fences). Grid barrier =
// per-block flag array + parallel 64-lane poll, BOUNDED (timeout -> 1e9
// marker in d_out so starvation is distinguishable from launch failure).
// 256 blocks x 256 thr = 1 block/CU, grid == #CUs => co-resident.
// Diagonal pipeline: super-step s = L1(t=s) on blocks 128..255, L2(t=s-1) on 0..127.

#define B_ 512
#define T_ 168
#define I_ 64
#define H_ 256
#define NBLK 256
#define KP 512                    // padded GEMM depth (both layers)

typedef __attribute__((ext_vector_type(8))) short short8;
typedef __attribute__((ext_vector_type(4))) float f32x4;
typedef unsigned short u16;
typedef unsigned int u32;
typedef unsigned long long u64;

__device__ __forceinline__ u16 f2bf(float f) {           // RNE
    unsigned u = __float_as_uint(f);
    return (u16)((u + 0x7fff + ((u >> 16) & 1)) >> 16);
}
__device__ __forceinline__ float bf2f(u16 b) { return __uint_as_float(((unsigned)b) << 16); }
__device__ __forceinline__ float sigm(float x) { return 1.f / (1.f + __expf(-x)); }
__device__ __forceinline__ float tanh_c(float x) {
    float xc = fminf(fmaxf(x, -15.f), 15.f);
    float e = __expf(2.f * xc);
    return (e - 1.f) / (e + 1.f);
}

// W packed [col][KP], col = gate*256+jh (gate order i,f,g,o), bf16 hi/lo,
// zero-padded for k >= Kreal.
__global__ void prep_w(const float* __restrict__ W_ih, const float* __restrict__ W_hh,
                       const float* __restrict__ b_ih, const float* __restrict__ b_hh,
                       u16* __restrict__ Whi, u16* __restrict__ Wlo, float* __restrict__ BP,
                       int Kreal, int I) {
    int j = blockIdx.y;                            // 0..1023
    int k = blockIdx.x * 256 + threadIdx.x;        // 0..511
    float v = 0.f;
    if (k < Kreal) v = (k < I) ? W_ih[(size_t)j * I + k] : W_hh[(size_t)j * H_ + (k - I)];
    u16 hi = f2bf(v);
    Whi[(size_t)j * KP + k] = hi;
    Wlo[(size_t)j * KP + k] = f2bf(v - bf2f(hi));
    if (blockIdx.x == 0 && threadIdx.x == 0) BP[j] = b_ih[j] + b_hh[j];
}

// x [b][t][i] fp32 -> Xp [t][b][i] packed (hi | lo<<16)
__global__ void prep_x_t(const float* __restrict__ x, u32* __restrict__ Xp) {
    int n = B_ * T_ * I_;
    for (int idx = blockIdx.x * blockDim.x + threadIdx.x; idx < n; idx += gridDim.x * blockDim.x) {
        float v = x[idx];
        int i = idx & 63, bt = idx >> 6;
        int t = bt % T_, b = bt / T_;
        u16 hi = f2bf(v);
        u16 lo = f2bf(v - bf2f(hi));
        Xp[((size_t)t * B_ + b) * I_ + i] = (u32)hi | ((u32)lo << 16);
    }
}

// 4 u64 (8 packed dwords) -> hi/lo short8 A-fragments
__device__ __forceinline__ void unpack8(const u64 q[4], short8& hi, short8& lo) {
    union { u32 u[4]; short8 s; } Hh, Ll;
#pragma unroll
    for (int i = 0; i < 4; ++i) {
        u32 e = (u32)q[i];
        u32 o = (u32)(q[i] >> 32);
        Hh.u[i] = (e & 0xFFFFu) | (o << 16);
        Ll.u[i] = (e >> 16) | (o & 0xFFFF0000u);
    }
    hi = Hh.s; lo = Ll.s;
}

struct PArgs {
    const u32* Xp;
    u32 *Hp1[2], *Hp2[2];          // packed h, [b][jh] dwords
    const u16 *W1hi, *W1lo, *W2hi, *W2lo;
    const float *BP1, *BP2;
    float* out;
    u32* flags;
};

__global__ __launch_bounds__(256, 1) void lstm_persist(PArgs a) {
    __shared__ float red[4][3][4][64][4];   // [msub][srcslot][gate][lane][4] = 48KB
    __shared__ int sh_dead;

    const int blk  = blockIdx.x;
    const bool isL1 = blk >= 128;
    const int sub  = isL1 ? (blk - 128) : blk;
    const int bg   = sub & 7;
    const int jh0  = (sub >> 3) << 4;
    const int b0   = bg * 64;
    const int tid  = threadIdx.x;
    const int wv   = tid >> 6;             // K-slice 0..3
    const int lane = tid & 63;
    const int lm   = lane & 15;
    const int lk8  = (lane >> 4) << 3;
    const int jh   = jh0 + lm;

    if (tid == 0) sh_dead = 0;

    // ---- one-time: W slice -> VGPRs (plain cached loads) ----
    const u16* Whi = isL1 ? a.W1hi : a.W2hi;
    const u16* Wlo = isL1 ? a.W1lo : a.W2lo;
    const float* BP = isL1 ? a.BP1 : a.BP2;
    short8 wh[4][4], wl[4][4];             // [win][gate]
#pragma unroll
    for (int w = 0; w < 4; ++w)
#pragma unroll
        for (int g = 0; g < 4; ++g) {
            size_t o = (size_t)(g * 256 + jh) * KP + wv * 128 + w * 32 + lk8;
            wh[w][g] = *(const short8*)(Whi + o);
            wl[w][g] = *(const short8*)(Wlo + o);
        }
    const float bi_ = BP[jh], bf_ = BP[H_ + jh], bg_ = BP[2 * H_ + jh], bo_ = BP[3 * H_ + jh];
    float creg[4] = {0.f, 0.f, 0.f, 0.f};
    bool dead = false;

    for (int s = 0; s <= T_; ++s) {
        const int t = isL1 ? s : (s - 1);
        const bool active = (isL1 ? (t < T_) : (t >= 0)) && !dead;
        const int wp = t & 1, rp = wp ^ 1;

        f32x4 acc[4][4];
        if (active) {
            // per-window source tables (wave-uniform, fully unrolled -> registers)
            const u32* sp[4]; int koff[4], strd[4];
#pragma unroll
            for (int w = 0; w < 4; ++w) {
                int k = wv * 128 + w * 32;
                if (isL1) {
                    if (k < 64) { sp[w] = a.Xp + (size_t)t * B_ * I_; koff[w] = k; strd[w] = I_; }
                    else        { sp[w] = a.Hp1[rp]; koff[w] = (k - 64) & 255; strd[w] = H_; }
                } else {
                    if (k < 256) { sp[w] = a.Hp1[wp]; koff[w] = k;        strd[w] = H_; }
                    else         { sp[w] = a.Hp2[rp]; koff[w] = k - 256;  strd[w] = H_; }
                }
            }
#pragma unroll
            for (int m = 0; m < 4; ++m)
#pragma unroll
                for (int g = 0; g < 4; ++g) acc[m][g] = (f32x4){0.f, 0.f, 0.f, 0.f};

            u64 A0[4][4], A1[4][4];        // double-buffered A fragments
            auto LOADW = [&](u64 (&buf)[4][4], int w) {
#pragma unroll
                for (int m = 0; m < 4; ++m) {
                    const u32* q = sp[w] + (size_t)(b0 + m * 16 + lm) * strd[w] + koff[w] + lk8;
#pragma unroll
                    for (int i = 0; i < 4; ++i)
                        buf[m][i] = __hip_atomic_load((const u64*)q + i,
                                                      __ATOMIC_RELAXED, __HIP_MEMORY_SCOPE_AGENT);
                }
            };
            auto COMPW = [&](u64 (&buf)[4][4], int w) {
#pragma unroll
                for (int m = 0; m < 4; ++m) {
                    short8 ah, al;
                    unpack8(buf[m], ah, al);
#pragma unroll
                    for (int g = 0; g < 4; ++g) {
                        acc[m][g] = __builtin_amdgcn_mfma_f32_16x16x32_bf16(ah, wh[w][g], acc[m][g], 0, 0, 0);
                        acc[m][g] = __builtin_amdgcn_mfma_f32_16x16x32_bf16(al, wh[w][g], acc[m][g], 0, 0, 0);
                        acc[m][g] = __builtin_amdgcn_mfma_f32_16x16x32_bf16(ah, wl[w][g], acc[m][g], 0, 0, 0);
                    }
                }
            };
            LOADW(A0, 0); LOADW(A1, 1);
            COMPW(A0, 0); LOADW(A0, 2);
            COMPW(A1, 1); LOADW(A1, 3);
            COMPW(A0, 2);
            COMPW(A1, 3);

            // stage partials for other waves' msubs (slot = sv - (sv > m))
#pragma unroll
            for (int m = 0; m < 4; ++m)
                if (m != wv) {
                    const int slot = (wv > m) ? (wv - 1) : wv;
#pragma unroll
                    for (int g = 0; g < 4; ++g)
                        *(f32x4*)&red[m][slot][g][lane][0] = acc[m][g];
                }
        }
        __syncthreads();
        if (active) {
            // reduce own msub + epilogue
            f32x4 r[4];
#pragma unroll
            for (int g = 0; g < 4; ++g) r[g] = acc[wv][g];
#pragma unroll
            for (int sv = 0; sv < 4; ++sv)
                if (sv != wv) {
                    const int slot = (sv > wv) ? (sv - 1) : sv;
#pragma unroll
                    for (int g = 0; g < 4; ++g)
                        r[g] += *(const f32x4*)&red[wv][slot][g][lane][0];
                }

            u32* HW = isL1 ? a.Hp1[wp] : a.Hp2[wp];
#pragma unroll
            for (int i = 0; i < 4; ++i) {
                const int b = b0 + wv * 16 + ((lane >> 4) << 2) + i;
                float gi = r[0][i] + bi_;
                float gf = r[1][i] + bf_;
                float gg = r[2][i] + bg_;
                float go = r[3][i] + bo_;
                float si = sigm(gi), sf = sigm(gf), tg = tanh_c(gg), so = sigm(go);
                float cn = sf * creg[i] + si * tg;
                creg[i] = cn;
                float h = so * tanh_c(cn);
                u16 h16 = f2bf(h);
                u16 l16 = f2bf(h - bf2f(h16));
                __hip_atomic_store(HW + (size_t)b * H_ + jh, (u32)h16 | ((u32)l16 << 16),
                                   __ATOMIC_RELAXED, __HIP_MEMORY_SCOPE_AGENT);
                if (!isL1) a.out[((size_t)b * T_ + t) * H_ + jh] = h;
            }
        }
        if (s < T_) {
            asm volatile("s_waitcnt vmcnt(0)" ::: "memory");   // drain own H stores
            __syncthreads();
            if (tid == 0)
                __hip_atomic_store(a.flags + blk, (u32)(s + 1),
                                   __ATOMIC_RELAXED, __HIP_MEMORY_SCOPE_AGENT);
            if (wv == 0 && !dead) {
                const u32 tgt = (u32)(s + 1);
                int it = 0; bool timeout = false;
                for (;;) {
                    u32 v0 = __hip_atomic_load(a.flags + lane * 4 + 0, __ATOMIC_RELAXED, __HIP_MEMORY_SCOPE_AGENT);
                    u32 v1 = __hip_atomic_load(a.flags + lane * 4 + 1, __ATOMIC_RELAXED, __HIP_MEMORY_SCOPE_AGENT);
                    u32 v2 = __hip_atomic_load(a.flags + lane * 4 + 2, __ATOMIC_RELAXED, __HIP_MEMORY_SCOPE_AGENT);
                    u32 v3 = __hip_atomic_load(a.flags + lane * 4 + 3, __ATOMIC_RELAXED, __HIP_MEMORY_SCOPE_AGENT);
                    if (__all(v0 >= tgt && v1 >= tgt && v2 >= tgt && v3 >= tgt)) break;
                    if (++it > 60000) { timeout = true; break; }
                    __builtin_amdgcn_s_sleep(2);
                }
                if (timeout && lane == 0) {
                    sh_dead = 1;
                    a.out[blk] = 1e9f;     // starvation marker (diagnosable absmax)
                }
            }
            __syncthreads();
            if (sh_dead) dead = true;
        }
    }
}

extern "C" void kernel_launch(void* const* d_in, const int* in_sizes, int n_in,
                              void* d_out, int out_size, void* d_ws, size_t ws_size,
                              hipStream_t stream) {
    const float* x     = (const float*)d_in[0];
    const float* W_ih1 = (const float*)d_in[1];
    const float* W_hh1 = (const float*)d_in[2];
    const float* b_ih1 = (const float*)d_in[3];
    const float* b_hh1 = (const float*)d_in[4];
    const float* W_ih2 = (const float*)d_in[5];
    const float* W_hh2 = (const float*)d_in[6];
    const float* b_ih2 = (const float*)d_in[7];
    const float* b_hh2 = (const float*)d_in[8];
    (void)in_sizes; (void)n_in; (void)out_size; (void)ws_size;

    size_t off = 0;
    char* base = (char*)d_ws;
    auto alloc = [&](size_t bytes) { void* p = base + off; off = (off + bytes + 255) & ~(size_t)255; return p; };

    u16* W1hi = (u16*)alloc((size_t)1024 * KP * 2);
    u16* W1lo = (u16*)alloc((size_t)1024 * KP * 2);
    u16* W2hi = (u16*)alloc((size_t)1024 * KP * 2);
    u16* W2lo = (u16*)alloc((size_t)1024 * KP * 2);
    float* BP1 = (float*)alloc(1024 * 4);
    float* BP2 = (float*)alloc(1024 * 4);
    u32* Xp = (u32*)alloc((size_t)B_ * T_ * I_ * 4);

    // zero-init region: flags + packed H double-buffers
    char* state0 = base + off;
    PArgs pa;
    pa.flags = (u32*)alloc(NBLK * 4);
    const size_t HPB = (size_t)B_ * H_ * 4;    // 512 KB each
    pa.Hp1[0] = (u32*)alloc(HPB); pa.Hp1[1] = (u32*)alloc(HPB);
    pa.Hp2[0] = (u32*)alloc(HPB); pa.Hp2[1] = (u32*)alloc(HPB);
    size_t stateBytes = (size_t)((base + off) - state0);

    hipMemsetAsync(state0, 0, stateBytes, stream);
    prep_w<<<dim3(2, 1024), 256, 0, stream>>>(W_ih1, W_hh1, b_ih1, b_hh1, W1hi, W1lo, BP1, I_ + H_, I_);
    prep_w<<<dim3(2, 1024), 256, 0, stream>>>(W_ih2, W_hh2, b_ih2, b_hh2, W2hi, W2lo, BP2, 2 * H_, H_);
    prep_x_t<<<512, 256, 0, stream>>>(x, Xp);

    pa.Xp = Xp;
    pa.W1hi = W1hi; pa.W1lo = W1lo; pa.W2hi = W2hi; pa.W2lo = W2lo;
    pa.BP1 = BP1; pa.BP2 = BP2;
    pa.out = (float*)d_out;

    lstm_persist<<<dim3(NBLK), dim3(256), 0, stream>>>(pa);
}